// Round 3
// baseline (1227.381 us; speedup 1.0000x reference)
//
#include <hip/hip_runtime.h>
#include <hip/hip_bf16.h>

#define B 8
#define L 2048
#define D 1024

typedef __bf16 bf16x8 __attribute__((ext_vector_type(8)));
typedef __bf16 bf16x4 __attribute__((ext_vector_type(4)));
typedef float f32x4 __attribute__((ext_vector_type(4)));

typedef __attribute__((address_space(3))) char lds_char;
typedef const __attribute__((address_space(1))) char glob_char;

// ===========================================================================
// ROUND-3 MEASUREMENT BUILD: the whole 4-kernel pipeline is launched 5x
// (all kernels are pure functions of their inputs -> bit-identical outputs).
// dur = F + 5*K  where F = fixed harness cost inside the timed region and
// K = controllable kernel total.  K = (dur - 493.6)/4.
// Kernel bodies are byte-identical to round 2.
// ===========================================================================

// ---------------------------------------------------------------------------
// K1: e[b*L + j] = exp(dot(k[b,j,:], W2) + b2)
// ---------------------------------------------------------------------------
__global__ __launch_bounds__(256) void proj_kernel(const float* __restrict__ k,
                                                   const float* __restrict__ W2,
                                                   const float* __restrict__ b2,
                                                   float* __restrict__ e) {
    int t = threadIdx.x;
    int wave = t >> 6, lane = t & 63;
    int row = blockIdx.x * 4 + wave;      // 0 .. B*L-1
    const float4* k4 = (const float4*)(k + (size_t)row * D);
    const float4* w4 = (const float4*)W2;
    float p = 0.f;
#pragma unroll
    for (int s = 0; s < 4; s++) {
        float4 a = k4[s * 64 + lane];
        float4 w = w4[s * 64 + lane];
        p += a.x * w.x + a.y * w.y + a.z * w.z + a.w * w.w;
    }
    for (int off = 32; off > 0; off >>= 1)
        p += __shfl_down(p, off, 64);
    if (lane == 0) e[row] = __expf(p + b2[0]);
}

// ---------------------------------------------------------------------------
// K2: vT_bf16[b][d][j] = bf16(v[b][j][d])   (32x32 LDS tile transpose)
// ---------------------------------------------------------------------------
__global__ __launch_bounds__(256) void transpose_v(const float* __restrict__ v,
                                                   __bf16* __restrict__ vT) {
    __shared__ float tile[32][33];
    int b = blockIdx.z;
    int j0 = blockIdx.y * 32;
    int d0 = blockIdx.x * 32;
    int t = threadIdx.x;
    int jl = t >> 3;               // 0..31
    int dl = (t & 7) * 4;          // 0,4,..,28
    float4 val = *(const float4*)(v + ((size_t)b * L + j0 + jl) * D + d0 + dl);
    tile[jl][dl + 0] = val.x;
    tile[jl][dl + 1] = val.y;
    tile[jl][dl + 2] = val.z;
    tile[jl][dl + 3] = val.w;
    __syncthreads();
    int dl2 = t >> 3;              // 0..31
    int jl2 = (t & 7) * 4;         // 0,4,..,28
    bf16x4 o;
    o[0] = (__bf16)tile[jl2 + 0][dl2];
    o[1] = (__bf16)tile[jl2 + 1][dl2];
    o[2] = (__bf16)tile[jl2 + 2][dl2];
    o[3] = (__bf16)tile[jl2 + 3][dl2];
    *(bf16x4*)(vT + ((size_t)b * D + d0 + dl2) * L + j0 + jl2) = o;
}

// ---------------------------------------------------------------------------
// K3: per (b,i) row: w[j] = mask ? 0 : e[j]; Z = sum w; write attn + P.
// ---------------------------------------------------------------------------
__global__ __launch_bounds__(256) void row_kernel(const int* __restrict__ mask,
                                                  const float* __restrict__ e,
                                                  float* __restrict__ attn,
                                                  __bf16* __restrict__ P) {
    __shared__ float red[4];
    __shared__ float zsh;
    int bid = blockIdx.x;          // b*L + i
    int b = bid >> 11;             // L = 2048
    int t = threadIdx.x;
    const int4* m4 = (const int4*)(mask + (size_t)bid * L);
    const float4* e4 = (const float4*)(e + (size_t)b * L);
    float4 wv[2];
    float z = 0.f;
#pragma unroll
    for (int s = 0; s < 2; s++) {
        int idx = s * 256 + t;
        int4 mm = m4[idx];
        float4 ee = e4[idx];
        float4 ww;
        ww.x = mm.x ? 0.f : ee.x;
        ww.y = mm.y ? 0.f : ee.y;
        ww.z = mm.z ? 0.f : ee.z;
        ww.w = mm.w ? 0.f : ee.w;
        wv[s] = ww;
        z += ww.x + ww.y + ww.z + ww.w;
    }
    for (int off = 32; off > 0; off >>= 1)
        z += __shfl_down(z, off, 64);
    int wid = t >> 6, lane = t & 63;
    if (lane == 0) red[wid] = z;
    __syncthreads();
    if (t == 0) zsh = 1.f / (red[0] + red[1] + red[2] + red[3]);
    __syncthreads();
    float invZ = zsh;
    float4* a4 = (float4*)(attn + (size_t)bid * L);
    __bf16* prow = P + (size_t)bid * L;
#pragma unroll
    for (int s = 0; s < 2; s++) {
        int idx = s * 256 + t;
        float4 aa;
        aa.x = wv[s].x * invZ;
        aa.y = wv[s].y * invZ;
        aa.z = wv[s].z * invZ;
        aa.w = wv[s].w * invZ;
        a4[idx] = aa;
        bf16x4 pp;
        pp[0] = (__bf16)aa.x;
        pp[1] = (__bf16)aa.y;
        pp[2] = (__bf16)aa.z;
        pp[3] = (__bf16)aa.w;
        *(bf16x4*)(prow + idx * 4) = pp;
    }
}

// ---------------------------------------------------------------------------
// K4: out[b] = P[b] @ vT[b]^T (bf16 MFMA), round-2 structure unchanged:
// 256x256 tile, 8 waves, BK=32, 4-slot LDS ring, 2-deep prefetch,
// counted vmcnt, both-sides XOR swizzle, batch-per-XCD mapping, setprio.
// ---------------------------------------------------------------------------
#define BM 256
#define BN 256
#define BK 32
#define NT (L / BK)   // 64 K-tiles

__global__ __launch_bounds__(512, 2) void gemm_kernel(const __bf16* __restrict__ P,
                                                      const __bf16* __restrict__ vT,
                                                      float* __restrict__ out) {
    __shared__ __bf16 As[4][BM][BK];   // 64 KB
    __shared__ __bf16 Bs[4][BN][BK];   // 64 KB

    int p = blockIdx.x;             // 0..255
    int b = p & 7;                  // XCD id == batch
    int q = p >> 3;                 // 0..31 within XCD
    int i0 = (q & 7) * BM;          // 8 M-tiles
    int d0 = (q >> 3) * BN;         // 4 N-tiles

    int t = threadIdx.x;
    int wave = t >> 6, lane = t & 63;
    int wm = wave >> 2;             // 0..1  (M half)
    int wn = wave & 3;              // 0..3  (N quarter)
    const __bf16* Ab = P + ((size_t)b * L + i0) * L;    // row stride L (K dim)
    const __bf16* Bb = vT + ((size_t)b * D + d0) * L;   // row stride L (K dim)

    f32x4 acc[8][4];
#pragma unroll
    for (int ti = 0; ti < 8; ti++)
#pragma unroll
        for (int tj = 0; tj < 4; tj++)
            acc[ti][tj] = (f32x4){0.f, 0.f, 0.f, 0.f};

    int lrow = lane & 15;
    int kq = lane >> 4;             // 16B slot (0..3) of the 64B row

#define STAGE(tt) do {                                                         \
        int k0_ = (tt) * BK; int sl_ = (tt) & 3;                               \
        _Pragma("unroll")                                                      \
        for (int s_ = 0; s_ < 2; s_++) {                                       \
            int cbase_ = s_ * 512 + wave * 64;                                 \
            int c_ = cbase_ + lane;                                            \
            int r_ = c_ >> 2;                                                  \
            int off_ = ((c_ ^ (r_ >> 1)) & 3) * 8;                             \
            __builtin_amdgcn_global_load_lds(                                  \
                (glob_char*)(Ab + (size_t)r_ * L + k0_ + off_),                \
                (lds_char*)((char*)&As[sl_][0][0] + cbase_ * 16), 16, 0, 0);   \
            __builtin_amdgcn_global_load_lds(                                  \
                (glob_char*)(Bb + (size_t)r_ * L + k0_ + off_),                \
                (lds_char*)((char*)&Bs[sl_][0][0] + cbase_ * 16), 16, 0, 0);   \
        }                                                                      \
    } while (0)

#define COMPUTE(tt) do {                                                       \
        int sl_ = (tt) & 3;                                                    \
        bf16x8 af[8];                                                          \
        _Pragma("unroll")                                                      \
        for (int ti = 0; ti < 8; ti++) {                                       \
            int rowA_ = wm * 128 + ti * 16 + lrow;                             \
            af[ti] = *(const bf16x8*)((const char*)&As[sl_][0][0] +            \
                      rowA_ * 64 + (((kq ^ (rowA_ >> 1)) & 3) << 4));          \
        }                                                                      \
        __builtin_amdgcn_s_setprio(1);                                         \
        _Pragma("unroll")                                                      \
        for (int tj = 0; tj < 4; tj++) {                                       \
            int rowB_ = wn * 64 + tj * 16 + lrow;                              \
            bf16x8 bfr = *(const bf16x8*)((const char*)&Bs[sl_][0][0] +        \
                          rowB_ * 64 + (((kq ^ (rowB_ >> 1)) & 3) << 4));      \
            _Pragma("unroll")                                                  \
            for (int ti = 0; ti < 8; ti++)                                     \
                acc[ti][tj] = __builtin_amdgcn_mfma_f32_16x16x32_bf16(         \
                    af[ti], bfr, acc[ti][tj], 0, 0, 0);                        \
        }                                                                      \
        __builtin_amdgcn_s_setprio(0);                                         \
    } while (0)

    STAGE(0);
    STAGE(1);
    for (int tt = 0; tt < NT - 2; tt++) {
        STAGE(tt + 2);
        asm volatile("s_waitcnt vmcnt(8)" ::: "memory");  // tile tt landed
        __builtin_amdgcn_s_barrier();
        __builtin_amdgcn_sched_barrier(0);
        COMPUTE(tt);
    }
    asm volatile("s_waitcnt vmcnt(4)" ::: "memory");      // tile NT-2 landed
    __builtin_amdgcn_s_barrier();
    __builtin_amdgcn_sched_barrier(0);
    COMPUTE(NT - 2);
    asm volatile("s_waitcnt vmcnt(0)" ::: "memory");      // tile NT-1 landed
    __builtin_amdgcn_s_barrier();
    __builtin_amdgcn_sched_barrier(0);
    COMPUTE(NT - 1);

#undef STAGE
#undef COMPUTE

    int col = lane & 15;
    int rquad = (lane >> 4) * 4;
#pragma unroll
    for (int ti = 0; ti < 8; ti++) {
#pragma unroll
        for (int tj = 0; tj < 4; tj++) {
#pragma unroll
            for (int r = 0; r < 4; r++) {
                int row = i0 + wm * 128 + ti * 16 + rquad + r;
                int c2 = d0 + wn * 64 + tj * 16 + col;
                out[((size_t)b * L + row) * D + c2] = acc[ti][tj][r];
            }
        }
    }
}

// ---------------------------------------------------------------------------
extern "C" void kernel_launch(void* const* d_in, const int* in_sizes, int n_in,
                              void* d_out, int out_size, void* d_ws, size_t ws_size,
                              hipStream_t stream) {
    // inputs: q(0) k(1) v(2) attn_mask(3) W1(4) b1(5) W2(6) b2(7)
    const float* k = (const float*)d_in[1];
    const float* v = (const float*)d_in[2];
    const int* mask = (const int*)d_in[3];
    const float* W2 = (const float*)d_in[6];
    const float* b2 = (const float*)d_in[7];

    float* out = (float*)d_out;                     // [B,L,D]
    float* attn = out + (size_t)B * L * D;          // [B,L,L]

    // workspace carve
    char* wp = (char*)d_ws;
    float* e = (float*)wp;             wp += (size_t)B * L * 4;
    __bf16* vT = (__bf16*)wp;          wp += (size_t)B * D * L * 2;
    __bf16* P = (__bf16*)wp;           wp += (size_t)B * L * L * 2;

    // MEASUREMENT: 5x replication of the (idempotent) pipeline.
    // dur = F + 5*K  ->  K = (dur - 493.6)/4, F = fixed harness floor.
    for (int rep = 0; rep < 5; rep++) {
        proj_kernel<<<B * L / 4, 256, 0, stream>>>(k, W2, b2, e);
        transpose_v<<<dim3(D / 32, L / 32, B), 256, 0, stream>>>(v, vT);
        row_kernel<<<B * L, 256, 0, stream>>>(mask, e, attn, P);
        gemm_kernel<<<256, 512, 0, stream>>>(P, vT, out);
    }
}

// Round 4
// 785.351 us; speedup vs baseline: 1.5628x; 1.5628x over previous
//
#include <hip/hip_runtime.h>
#include <hip/hip_bf16.h>

#define B 8
#define L 2048
#define D 1024

typedef __bf16 bf16x8 __attribute__((ext_vector_type(8)));
typedef __bf16 bf16x4 __attribute__((ext_vector_type(4)));
typedef float f32x4 __attribute__((ext_vector_type(4)));

typedef __attribute__((address_space(3))) char lds_char;
typedef const __attribute__((address_space(1))) char glob_char;

// ===========================================================================
// ROUND-4 MEASUREMENT BUILD (split row vs gemm):
//   - row_kernel: ONE dispatch, grid x4 (bid = blockIdx.x & 16383) -> ~220us
//     single dispatch => surfaces in top-5 with its own counters.
//   - gemm: 3 sequential launches => gemm = (dur - 494.9 - 3*row)/2.
//   - proj, transpose: 1x, unchanged.
// Known from rounds 2-3: F ~= 312 us, K(1x pipeline) ~= 183 us.
// ===========================================================================

// ---------------------------------------------------------------------------
// K1: e[b*L + j] = exp(dot(k[b,j,:], W2) + b2)
// ---------------------------------------------------------------------------
__global__ __launch_bounds__(256) void proj_kernel(const float* __restrict__ k,
                                                   const float* __restrict__ W2,
                                                   const float* __restrict__ b2,
                                                   float* __restrict__ e) {
    int t = threadIdx.x;
    int wave = t >> 6, lane = t & 63;
    int row = blockIdx.x * 4 + wave;      // 0 .. B*L-1
    const float4* k4 = (const float4*)(k + (size_t)row * D);
    const float4* w4 = (const float4*)W2;
    float p = 0.f;
#pragma unroll
    for (int s = 0; s < 4; s++) {
        float4 a = k4[s * 64 + lane];
        float4 w = w4[s * 64 + lane];
        p += a.x * w.x + a.y * w.y + a.z * w.z + a.w * w.w;
    }
    for (int off = 32; off > 0; off >>= 1)
        p += __shfl_down(p, off, 64);
    if (lane == 0) e[row] = __expf(p + b2[0]);
}

// ---------------------------------------------------------------------------
// K2: vT_bf16[b][d][j] = bf16(v[b][j][d])   (32x32 LDS tile transpose)
// ---------------------------------------------------------------------------
__global__ __launch_bounds__(256) void transpose_v(const float* __restrict__ v,
                                                   __bf16* __restrict__ vT) {
    __shared__ float tile[32][33];
    int b = blockIdx.z;
    int j0 = blockIdx.y * 32;
    int d0 = blockIdx.x * 32;
    int t = threadIdx.x;
    int jl = t >> 3;               // 0..31
    int dl = (t & 7) * 4;          // 0,4,..,28
    float4 val = *(const float4*)(v + ((size_t)b * L + j0 + jl) * D + d0 + dl);
    tile[jl][dl + 0] = val.x;
    tile[jl][dl + 1] = val.y;
    tile[jl][dl + 2] = val.z;
    tile[jl][dl + 3] = val.w;
    __syncthreads();
    int dl2 = t >> 3;              // 0..31
    int jl2 = (t & 7) * 4;         // 0,4,..,28
    bf16x4 o;
    o[0] = (__bf16)tile[jl2 + 0][dl2];
    o[1] = (__bf16)tile[jl2 + 1][dl2];
    o[2] = (__bf16)tile[jl2 + 2][dl2];
    o[3] = (__bf16)tile[jl2 + 3][dl2];
    *(bf16x4*)(vT + ((size_t)b * D + d0 + dl2) * L + j0 + jl2) = o;
}

// ---------------------------------------------------------------------------
// K3: per (b,i) row: w[j] = mask ? 0 : e[j]; Z = sum w; write attn + P.
// MEASUREMENT: grid x4, bid = blockIdx.x & 16383 (duplicate blocks write
// identical values -> benign; surfaces this kernel in rocprof top-5).
// ---------------------------------------------------------------------------
__global__ __launch_bounds__(256) void row_kernel(const int* __restrict__ mask,
                                                  const float* __restrict__ e,
                                                  float* __restrict__ attn,
                                                  __bf16* __restrict__ P) {
    __shared__ float red[4];
    __shared__ float zsh;
    int bid = blockIdx.x & 16383;  // b*L + i  (x4 replication)
    int b = bid >> 11;             // L = 2048
    int t = threadIdx.x;
    const int4* m4 = (const int4*)(mask + (size_t)bid * L);
    const float4* e4 = (const float4*)(e + (size_t)b * L);
    float4 wv[2];
    float z = 0.f;
#pragma unroll
    for (int s = 0; s < 2; s++) {
        int idx = s * 256 + t;
        int4 mm = m4[idx];
        float4 ee = e4[idx];
        float4 ww;
        ww.x = mm.x ? 0.f : ee.x;
        ww.y = mm.y ? 0.f : ee.y;
        ww.z = mm.z ? 0.f : ee.z;
        ww.w = mm.w ? 0.f : ee.w;
        wv[s] = ww;
        z += ww.x + ww.y + ww.z + ww.w;
    }
    for (int off = 32; off > 0; off >>= 1)
        z += __shfl_down(z, off, 64);
    int wid = t >> 6, lane = t & 63;
    if (lane == 0) red[wid] = z;
    __syncthreads();
    if (t == 0) zsh = 1.f / (red[0] + red[1] + red[2] + red[3]);
    __syncthreads();
    float invZ = zsh;
    float4* a4 = (float4*)(attn + (size_t)bid * L);
    __bf16* prow = P + (size_t)bid * L;
#pragma unroll
    for (int s = 0; s < 2; s++) {
        int idx = s * 256 + t;
        float4 aa;
        aa.x = wv[s].x * invZ;
        aa.y = wv[s].y * invZ;
        aa.z = wv[s].z * invZ;
        aa.w = wv[s].w * invZ;
        a4[idx] = aa;
        bf16x4 pp;
        pp[0] = (__bf16)aa.x;
        pp[1] = (__bf16)aa.y;
        pp[2] = (__bf16)aa.z;
        pp[3] = (__bf16)aa.w;
        *(bf16x4*)(prow + idx * 4) = pp;
    }
}

// ---------------------------------------------------------------------------
// K4: out[b] = P[b] @ vT[b]^T (bf16 MFMA), round-2 structure unchanged.
// ---------------------------------------------------------------------------
#define BM 256
#define BN 256
#define BK 32
#define NT (L / BK)   // 64 K-tiles

__global__ __launch_bounds__(512, 2) void gemm_kernel(const __bf16* __restrict__ P,
                                                      const __bf16* __restrict__ vT,
                                                      float* __restrict__ out) {
    __shared__ __bf16 As[4][BM][BK];   // 64 KB
    __shared__ __bf16 Bs[4][BN][BK];   // 64 KB

    int p = blockIdx.x;             // 0..255
    int b = p & 7;                  // XCD id == batch
    int q = p >> 3;                 // 0..31 within XCD
    int i0 = (q & 7) * BM;          // 8 M-tiles
    int d0 = (q >> 3) * BN;         // 4 N-tiles

    int t = threadIdx.x;
    int wave = t >> 6, lane = t & 63;
    int wm = wave >> 2;             // 0..1  (M half)
    int wn = wave & 3;              // 0..3  (N quarter)
    const __bf16* Ab = P + ((size_t)b * L + i0) * L;    // row stride L (K dim)
    const __bf16* Bb = vT + ((size_t)b * D + d0) * L;   // row stride L (K dim)

    f32x4 acc[8][4];
#pragma unroll
    for (int ti = 0; ti < 8; ti++)
#pragma unroll
        for (int tj = 0; tj < 4; tj++)
            acc[ti][tj] = (f32x4){0.f, 0.f, 0.f, 0.f};

    int lrow = lane & 15;
    int kq = lane >> 4;             // 16B slot (0..3) of the 64B row

#define STAGE(tt) do {                                                         \
        int k0_ = (tt) * BK; int sl_ = (tt) & 3;                               \
        _Pragma("unroll")                                                      \
        for (int s_ = 0; s_ < 2; s_++) {                                       \
            int cbase_ = s_ * 512 + wave * 64;                                 \
            int c_ = cbase_ + lane;                                            \
            int r_ = c_ >> 2;                                                  \
            int off_ = ((c_ ^ (r_ >> 1)) & 3) * 8;                             \
            __builtin_amdgcn_global_load_lds(                                  \
                (glob_char*)(Ab + (size_t)r_ * L + k0_ + off_),                \
                (lds_char*)((char*)&As[sl_][0][0] + cbase_ * 16), 16, 0, 0);   \
            __builtin_amdgcn_global_load_lds(                                  \
                (glob_char*)(Bb + (size_t)r_ * L + k0_ + off_),                \
                (lds_char*)((char*)&Bs[sl_][0][0] + cbase_ * 16), 16, 0, 0);   \
        }                                                                      \
    } while (0)

#define COMPUTE(tt) do {                                                       \
        int sl_ = (tt) & 3;                                                    \
        bf16x8 af[8];                                                          \
        _Pragma("unroll")                                                      \
        for (int ti = 0; ti < 8; ti++) {                                       \
            int rowA_ = wm * 128 + ti * 16 + lrow;                             \
            af[ti] = *(const bf16x8*)((const char*)&As[sl_][0][0] +            \
                      rowA_ * 64 + (((kq ^ (rowA_ >> 1)) & 3) << 4));          \
        }                                                                      \
        __builtin_amdgcn_s_setprio(1);                                         \
        _Pragma("unroll")                                                      \
        for (int tj = 0; tj < 4; tj++) {                                       \
            int rowB_ = wn * 64 + tj * 16 + lrow;                              \
            bf16x8 bfr = *(const bf16x8*)((const char*)&Bs[sl_][0][0] +        \
                          rowB_ * 64 + (((kq ^ (rowB_ >> 1)) & 3) << 4));      \
            _Pragma("unroll")                                                  \
            for (int ti = 0; ti < 8; ti++)                                     \
                acc[ti][tj] = __builtin_amdgcn_mfma_f32_16x16x32_bf16(         \
                    af[ti], bfr, acc[ti][tj], 0, 0, 0);                        \
        }                                                                      \
        __builtin_amdgcn_s_setprio(0);                                         \
    } while (0)

    STAGE(0);
    STAGE(1);
    for (int tt = 0; tt < NT - 2; tt++) {
        STAGE(tt + 2);
        asm volatile("s_waitcnt vmcnt(8)" ::: "memory");  // tile tt landed
        __builtin_amdgcn_s_barrier();
        __builtin_amdgcn_sched_barrier(0);
        COMPUTE(tt);
    }
    asm volatile("s_waitcnt vmcnt(4)" ::: "memory");      // tile NT-2 landed
    __builtin_amdgcn_s_barrier();
    __builtin_amdgcn_sched_barrier(0);
    COMPUTE(NT - 2);
    asm volatile("s_waitcnt vmcnt(0)" ::: "memory");      // tile NT-1 landed
    __builtin_amdgcn_s_barrier();
    __builtin_amdgcn_sched_barrier(0);
    COMPUTE(NT - 1);

#undef STAGE
#undef COMPUTE

    int col = lane & 15;
    int rquad = (lane >> 4) * 4;
#pragma unroll
    for (int ti = 0; ti < 8; ti++) {
#pragma unroll
        for (int tj = 0; tj < 4; tj++) {
#pragma unroll
            for (int r = 0; r < 4; r++) {
                int row = i0 + wm * 128 + ti * 16 + rquad + r;
                int c2 = d0 + wn * 64 + tj * 16 + col;
                out[((size_t)b * L + row) * D + c2] = acc[ti][tj][r];
            }
        }
    }
}

// ---------------------------------------------------------------------------
extern "C" void kernel_launch(void* const* d_in, const int* in_sizes, int n_in,
                              void* d_out, int out_size, void* d_ws, size_t ws_size,
                              hipStream_t stream) {
    // inputs: q(0) k(1) v(2) attn_mask(3) W1(4) b1(5) W2(6) b2(7)
    const float* k = (const float*)d_in[1];
    const float* v = (const float*)d_in[2];
    const int* mask = (const int*)d_in[3];
    const float* W2 = (const float*)d_in[6];
    const float* b2 = (const float*)d_in[7];

    float* out = (float*)d_out;                     // [B,L,D]
    float* attn = out + (size_t)B * L * D;          // [B,L,L]

    // workspace carve
    char* wp = (char*)d_ws;
    float* e = (float*)wp;             wp += (size_t)B * L * 4;
    __bf16* vT = (__bf16*)wp;          wp += (size_t)B * D * L * 2;
    __bf16* P = (__bf16*)wp;           wp += (size_t)B * L * L * 2;

    proj_kernel<<<B * L / 4, 256, 0, stream>>>(k, W2, b2, e);
    transpose_v<<<dim3(D / 32, L / 32, B), 256, 0, stream>>>(v, vT);
    // MEASUREMENT: row x4 in ONE dispatch (surfaces in top-5 with counters)
    row_kernel<<<4 * B * L, 256, 0, stream>>>(mask, e, attn, P);
    // MEASUREMENT: gemm x3 sequential -> gemm = (dur - 494.9 - 3*row)/2
    gemm_kernel<<<256, 512, 0, stream>>>(P, vT, out);
    gemm_kernel<<<256, 512, 0, stream>>>(P, vT, out);
    gemm_kernel<<<256, 512, 0, stream>>>(P, vT, out);
}

// Round 5
// 471.804 us; speedup vs baseline: 2.6015x; 1.6646x over previous
//
#include <hip/hip_runtime.h>
#include <hip/hip_bf16.h>

#define B 8
#define L 2048
#define D 1024

typedef __bf16 bf16x8 __attribute__((ext_vector_type(8)));
typedef __bf16 bf16x4 __attribute__((ext_vector_type(4)));
typedef float f32x4 __attribute__((ext_vector_type(4)));
typedef int i32x4 __attribute__((ext_vector_type(4)));

typedef __attribute__((address_space(3))) char lds_char;
typedef const __attribute__((address_space(1))) char glob_char;

// ===========================================================================
// Round 5: optimization build (1x launches restored).
// Known decomposition: dur = F(~312us harness fills) + K(~183us kernels).
// K ~= proj+transpose(~26-40) + row(~60-73 @4.6TB/s) + gemm(~60-67 @~1.1PF).
// This round: wave-per-row row_kernel (no barriers, nt hints, grid-stride
// 2048 blocks) + proj/transpose merged into one launch. gemm untouched.
// ===========================================================================

// ---------------------------------------------------------------------------
// K1+K2 merged: blocks [0, 2048) = proj, blocks [2048, 18432) = transpose.
//   proj:      e[b*L + j] = exp(dot(k[b,j,:], W2) + b2)   (one wave per row)
//   transpose: vT_bf16[b][d][j] = bf16(v[b][j][d])        (32x32 LDS tile)
// Independent work; merged to remove a launch gap and the proj tail bubble.
// ---------------------------------------------------------------------------
__global__ __launch_bounds__(256) void pt_kernel(const float* __restrict__ k,
                                                 const float* __restrict__ W2,
                                                 const float* __restrict__ b2,
                                                 float* __restrict__ e,
                                                 const float* __restrict__ v,
                                                 __bf16* __restrict__ vT) {
    __shared__ float tile[32][33];
    int blk = blockIdx.x;
    int t = threadIdx.x;
    if (blk < B * L / 4) {
        // ---- proj ----
        int wave = t >> 6, lane = t & 63;
        int row = blk * 4 + wave;      // 0 .. B*L-1
        const float4* k4 = (const float4*)(k + (size_t)row * D);
        const float4* w4 = (const float4*)W2;
        float p = 0.f;
#pragma unroll
        for (int s = 0; s < 4; s++) {
            float4 a = k4[s * 64 + lane];
            float4 w = w4[s * 64 + lane];
            p += a.x * w.x + a.y * w.y + a.z * w.z + a.w * w.w;
        }
        for (int off = 32; off > 0; off >>= 1)
            p += __shfl_down(p, off, 64);
        if (lane == 0) e[row] = __expf(p + b2[0]);
    } else {
        // ---- transpose ----
        int tb = blk - B * L / 4;      // 0..16383
        int b = tb >> 11;              // 2048 tiles per batch (64 j x 32 d)
        int rem = tb & 2047;
        int j0 = (rem >> 5) * 32;
        int d0 = (rem & 31) * 32;
        int jl = t >> 3;               // 0..31
        int dl = (t & 7) * 4;          // 0,4,..,28
        float4 val = *(const float4*)(v + ((size_t)b * L + j0 + jl) * D + d0 + dl);
        tile[jl][dl + 0] = val.x;
        tile[jl][dl + 1] = val.y;
        tile[jl][dl + 2] = val.z;
        tile[jl][dl + 3] = val.w;
        __syncthreads();
        int dl2 = t >> 3;              // 0..31
        int jl2 = (t & 7) * 4;         // 0,4,..,28
        bf16x4 o;
        o[0] = (__bf16)tile[jl2 + 0][dl2];
        o[1] = (__bf16)tile[jl2 + 1][dl2];
        o[2] = (__bf16)tile[jl2 + 2][dl2];
        o[3] = (__bf16)tile[jl2 + 3][dl2];
        *(bf16x4*)(vT + ((size_t)b * D + d0 + dl2) * L + j0 + jl2) = o;
    }
}

// ---------------------------------------------------------------------------
// K3: per (b,i) row: w[j] = mask ? 0 : e[j]; Z = sum w; attn = w/Z (fp32),
//     P = bf16(w/Z).
// Round-5 rewrite: ONE WAVE per row (4 rows/block) -- butterfly __shfl_xor
// gives every lane Z with no LDS and no __syncthreads; grid-stride at 2048
// blocks (8/CU); nontemporal mask load + attn store (neither re-read; keeps
// L2 for e and P). Was 4.6 TB/s as block-per-row; target ~5.5-6.
// ---------------------------------------------------------------------------
__global__ __launch_bounds__(256) void row_kernel(const int* __restrict__ mask,
                                                  const float* __restrict__ e,
                                                  float* __restrict__ attn,
                                                  __bf16* __restrict__ P) {
    int t = threadIdx.x;
    int wid = t >> 6, lane = t & 63;
    for (int grp = blockIdx.x; grp < B * L / 4; grp += 2048) {
        int bid = grp * 4 + wid;       // row id: b*L + i
        int b = bid >> 11;             // L = 2048
        const i32x4* m4 = (const i32x4*)(mask + (size_t)bid * L);
        const f32x4* e4 = (const f32x4*)(e + (size_t)b * L);
        f32x4 wv[8];
        float z = 0.f;
#pragma unroll
        for (int s = 0; s < 8; s++) {
            int idx = s * 64 + lane;
            i32x4 mm = __builtin_nontemporal_load(&m4[idx]);
            f32x4 ee = e4[idx];
            f32x4 ww;
            ww.x = mm.x ? 0.f : ee.x;
            ww.y = mm.y ? 0.f : ee.y;
            ww.z = mm.z ? 0.f : ee.z;
            ww.w = mm.w ? 0.f : ee.w;
            wv[s] = ww;
            z += ww.x + ww.y + ww.z + ww.w;
        }
#pragma unroll
        for (int off = 32; off > 0; off >>= 1)
            z += __shfl_xor(z, off, 64);
        float invZ = 1.f / z;          // every lane holds Z after butterfly
        f32x4* a4 = (f32x4*)(attn + (size_t)bid * L);
        __bf16* prow = P + (size_t)bid * L;
#pragma unroll
        for (int s = 0; s < 8; s++) {
            int idx = s * 64 + lane;
            f32x4 aa;
            aa.x = wv[s].x * invZ;
            aa.y = wv[s].y * invZ;
            aa.z = wv[s].z * invZ;
            aa.w = wv[s].w * invZ;
            __builtin_nontemporal_store(aa, &a4[idx]);
            bf16x4 pp;
            pp[0] = (__bf16)aa.x;
            pp[1] = (__bf16)aa.y;
            pp[2] = (__bf16)aa.z;
            pp[3] = (__bf16)aa.w;
            *(bf16x4*)(prow + idx * 4) = pp;
        }
    }
}

// ---------------------------------------------------------------------------
// K4: out[b] = P[b] @ vT[b]^T (bf16 MFMA). Round-2 structure, UNTOUCHED
// (measured ~60-67us ~= 1.1 PF): 256x256 tile, 8 waves, BK=32, 4-slot LDS
// ring, 2-deep prefetch, counted vmcnt (never 0 in-loop), both-sides XOR
// swizzle, batch-per-XCD mapping, setprio around MFMA cluster.
// ---------------------------------------------------------------------------
#define BM 256
#define BN 256
#define BK 32
#define NT (L / BK)   // 64 K-tiles

__global__ __launch_bounds__(512, 2) void gemm_kernel(const __bf16* __restrict__ P,
                                                      const __bf16* __restrict__ vT,
                                                      float* __restrict__ out) {
    __shared__ __bf16 As[4][BM][BK];   // 64 KB
    __shared__ __bf16 Bs[4][BN][BK];   // 64 KB

    int p = blockIdx.x;             // 0..255
    int b = p & 7;                  // XCD id == batch
    int q = p >> 3;                 // 0..31 within XCD
    int i0 = (q & 7) * BM;          // 8 M-tiles
    int d0 = (q >> 3) * BN;         // 4 N-tiles

    int t = threadIdx.x;
    int wave = t >> 6, lane = t & 63;
    int wm = wave >> 2;             // 0..1  (M half)
    int wn = wave & 3;              // 0..3  (N quarter)
    const __bf16* Ab = P + ((size_t)b * L + i0) * L;    // row stride L (K dim)
    const __bf16* Bb = vT + ((size_t)b * D + d0) * L;   // row stride L (K dim)

    f32x4 acc[8][4];
#pragma unroll
    for (int ti = 0; ti < 8; ti++)
#pragma unroll
        for (int tj = 0; tj < 4; tj++)
            acc[ti][tj] = (f32x4){0.f, 0.f, 0.f, 0.f};

    int lrow = lane & 15;
    int kq = lane >> 4;             // 16B slot (0..3) of the 64B row

#define STAGE(tt) do {                                                         \
        int k0_ = (tt) * BK; int sl_ = (tt) & 3;                               \
        _Pragma("unroll")                                                      \
        for (int s_ = 0; s_ < 2; s_++) {                                       \
            int cbase_ = s_ * 512 + wave * 64;                                 \
            int c_ = cbase_ + lane;                                            \
            int r_ = c_ >> 2;                                                  \
            int off_ = ((c_ ^ (r_ >> 1)) & 3) * 8;                             \
            __builtin_amdgcn_global_load_lds(                                  \
                (glob_char*)(Ab + (size_t)r_ * L + k0_ + off_),                \
                (lds_char*)((char*)&As[sl_][0][0] + cbase_ * 16), 16, 0, 0);   \
            __builtin_amdgcn_global_load_lds(                                  \
                (glob_char*)(Bb + (size_t)r_ * L + k0_ + off_),                \
                (lds_char*)((char*)&Bs[sl_][0][0] + cbase_ * 16), 16, 0, 0);   \
        }                                                                      \
    } while (0)

#define COMPUTE(tt) do {                                                       \
        int sl_ = (tt) & 3;                                                    \
        bf16x8 af[8];                                                          \
        _Pragma("unroll")                                                      \
        for (int ti = 0; ti < 8; ti++) {                                       \
            int rowA_ = wm * 128 + ti * 16 + lrow;                             \
            af[ti] = *(const bf16x8*)((const char*)&As[sl_][0][0] +            \
                      rowA_ * 64 + (((kq ^ (rowA_ >> 1)) & 3) << 4));          \
        }                                                                      \
        __builtin_amdgcn_s_setprio(1);                                         \
        _Pragma("unroll")                                                      \
        for (int tj = 0; tj < 4; tj++) {                                       \
            int rowB_ = wn * 64 + tj * 16 + lrow;                              \
            bf16x8 bfr = *(const bf16x8*)((const char*)&Bs[sl_][0][0] +        \
                          rowB_ * 64 + (((kq ^ (rowB_ >> 1)) & 3) << 4));      \
            _Pragma("unroll")                                                  \
            for (int ti = 0; ti < 8; ti++)                                     \
                acc[ti][tj] = __builtin_amdgcn_mfma_f32_16x16x32_bf16(         \
                    af[ti], bfr, acc[ti][tj], 0, 0, 0);                        \
        }                                                                      \
        __builtin_amdgcn_s_setprio(0);                                         \
    } while (0)

    STAGE(0);
    STAGE(1);
    for (int tt = 0; tt < NT - 2; tt++) {
        STAGE(tt + 2);
        asm volatile("s_waitcnt vmcnt(8)" ::: "memory");  // tile tt landed
        __builtin_amdgcn_s_barrier();
        __builtin_amdgcn_sched_barrier(0);
        COMPUTE(tt);
    }
    asm volatile("s_waitcnt vmcnt(4)" ::: "memory");      // tile NT-2 landed
    __builtin_amdgcn_s_barrier();
    __builtin_amdgcn_sched_barrier(0);
    COMPUTE(NT - 2);
    asm volatile("s_waitcnt vmcnt(0)" ::: "memory");      // tile NT-1 landed
    __builtin_amdgcn_s_barrier();
    __builtin_amdgcn_sched_barrier(0);
    COMPUTE(NT - 1);

#undef STAGE
#undef COMPUTE

    int col = lane & 15;
    int rquad = (lane >> 4) * 4;
#pragma unroll
    for (int ti = 0; ti < 8; ti++) {
#pragma unroll
        for (int tj = 0; tj < 4; tj++) {
#pragma unroll
            for (int r = 0; r < 4; r++) {
                int row = i0 + wm * 128 + ti * 16 + rquad + r;
                int c2 = d0 + wn * 64 + tj * 16 + col;
                out[((size_t)b * L + row) * D + c2] = acc[ti][tj][r];
            }
        }
    }
}

// ---------------------------------------------------------------------------
extern "C" void kernel_launch(void* const* d_in, const int* in_sizes, int n_in,
                              void* d_out, int out_size, void* d_ws, size_t ws_size,
                              hipStream_t stream) {
    // inputs: q(0) k(1) v(2) attn_mask(3) W1(4) b1(5) W2(6) b2(7)
    const float* k = (const float*)d_in[1];
    const float* v = (const float*)d_in[2];
    const int* mask = (const int*)d_in[3];
    const float* W2 = (const float*)d_in[6];
    const float* b2 = (const float*)d_in[7];

    float* out = (float*)d_out;                     // [B,L,D]
    float* attn = out + (size_t)B * L * D;          // [B,L,L]

    // workspace carve
    char* wp = (char*)d_ws;
    float* e = (float*)wp;             wp += (size_t)B * L * 4;
    __bf16* vT = (__bf16*)wp;          wp += (size_t)B * D * L * 2;
    __bf16* P = (__bf16*)wp;           wp += (size_t)B * L * L * 2;

    pt_kernel<<<B * L / 4 + (B * L / 32) * (D / 32), 256, 0, stream>>>(k, W2, b2, e, v, vT);
    row_kernel<<<2048, 256, 0, stream>>>(mask, e, attn, P);
    gemm_kernel<<<256, 512, 0, stream>>>(P, vT, out);
}